// Round 7
// baseline (1113.846 us; speedup 1.0000x reference)
//
#include <hip/hip_runtime.h>
#include <stdint.h>

#define NTOK 16384   // B*S = 4*4096
#define DIN 512
#define DOUT 512
#define KE 8
#define BM 128
#define BN 128
#define BK 64
#define ESTRIDE (DOUT * DIN)

#define GATE_BLOCKS 4096           // 1 token/wave, 4 waves/block
#define WCONV_BLOCKS 1024          // 2M elements / (256*8)

typedef unsigned short u16;
typedef u16 u16x8 __attribute__((ext_vector_type(8)));
typedef __bf16 bf16x8 __attribute__((ext_vector_type(8)));
typedef float f32x4 __attribute__((ext_vector_type(4)));

__device__ __forceinline__ u16 f2bf(float f) {
  union { float f; unsigned u; } v; v.f = f;
  unsigned r = v.u + 0x7FFFu + ((v.u >> 16) & 1u);   // RNE; inputs are finite
  return (u16)(r >> 16);
}

// async global->LDS, 16B per lane; LDS dest is wave-uniform base + lane*16
#define GLOAD_LDS16(gp, lp)                                              \
  __builtin_amdgcn_global_load_lds(                                     \
      (__attribute__((address_space(1))) void*)(gp),                    \
      (__attribute__((address_space(3))) void*)(lp), 16, 0, 0)

// ---------------------------------------------------------------------------
// Kernel 1a: gating softmax + x fp32->bf16 cast. One token per wave.
// Coeffs written TRANSPOSED: coeffsT[e][tok].
// ---------------------------------------------------------------------------
__global__ __launch_bounds__(256) void gate_kernel(
    const float* __restrict__ x, const float* __restrict__ mw,
    const float* __restrict__ mb, u16* __restrict__ xbf,
    float* __restrict__ coeffsT) {
  const int tid = threadIdx.x;
  const int wave = tid >> 6, lane = tid & 63;
  const int tok = blockIdx.x * 4 + wave;

  // mixer weight slice for this lane, in registers (broadcast loads)
  float mwr[KE][8];
#pragma unroll
  for (int k = 0; k < KE; ++k) {
    const float* wr = &mw[k * DIN + lane * 8];
    const float4 w0 = *(const float4*)wr;
    const float4 w1 = *(const float4*)(wr + 4);
    mwr[k][0] = w0.x; mwr[k][1] = w0.y; mwr[k][2] = w0.z; mwr[k][3] = w0.w;
    mwr[k][4] = w1.x; mwr[k][5] = w1.y; mwr[k][6] = w1.z; mwr[k][7] = w1.w;
  }
  float mbr[KE];
#pragma unroll
  for (int k = 0; k < KE; ++k) mbr[k] = mb[k];

  const float* xr = x + (size_t)tok * DIN + lane * 8;
  const float4 xa = *(const float4*)xr;
  const float4 xb = *(const float4*)(xr + 4);

  u16x8 p;
  p[0] = f2bf(xa.x); p[1] = f2bf(xa.y); p[2] = f2bf(xa.z); p[3] = f2bf(xa.w);
  p[4] = f2bf(xb.x); p[5] = f2bf(xb.y); p[6] = f2bf(xb.z); p[7] = f2bf(xb.w);
  *(u16x8*)(xbf + (size_t)tok * DIN + lane * 8) = p;

  float lg[KE];
#pragma unroll
  for (int k = 0; k < KE; ++k) {
    lg[k] = xa.x * mwr[k][0] + xa.y * mwr[k][1] + xa.z * mwr[k][2] +
            xa.w * mwr[k][3] + xb.x * mwr[k][4] + xb.y * mwr[k][5] +
            xb.z * mwr[k][6] + xb.w * mwr[k][7];
  }
#pragma unroll
  for (int off = 32; off; off >>= 1)
#pragma unroll
    for (int k = 0; k < KE; ++k) lg[k] += __shfl_xor(lg[k], off);

#pragma unroll
  for (int k = 0; k < KE; ++k) lg[k] += mbr[k];
  float mx = lg[0];
#pragma unroll
  for (int k = 1; k < KE; ++k) mx = fmaxf(mx, lg[k]);
  float s = 0.f;
#pragma unroll
  for (int k = 0; k < KE; ++k) { lg[k] = __expf(lg[k] - mx); s += lg[k]; }
  const float inv = 1.f / s;
  if (lane == 0) {
#pragma unroll
    for (int k = 0; k < KE; ++k) coeffsT[(size_t)k * NTOK + tok] = lg[k] * inv;
  }
}

// ---------------------------------------------------------------------------
// Kernel 1b: expert-weight fp32->bf16 cast (8 elements/thread).
// ---------------------------------------------------------------------------
__global__ __launch_bounds__(256) void wcast_kernel(
    const float* __restrict__ ew, u16* __restrict__ wbf) {
  const size_t i = ((size_t)blockIdx.x * 256 + threadIdx.x) * 8;
  const float4 a = *(const float4*)&ew[i];
  const float4 b = *(const float4*)&ew[i + 4];
  u16x8 p;
  p[0] = f2bf(a.x); p[1] = f2bf(a.y); p[2] = f2bf(a.z); p[3] = f2bf(a.w);
  p[4] = f2bf(b.x); p[5] = f2bf(b.y); p[6] = f2bf(b.z); p[7] = f2bf(b.w);
  *(u16x8*)&wbf[i] = p;
}

// ---------------------------------------------------------------------------
// Kernel 2: MoE GEMM v7 (resubmit; R5/R6 were container-infra failures,
// kernel unmeasured — audited: all GLOADs boundary-exact in-bounds, all
// barriers uniform, swizzle store/read keys re-derived consistent).
// h-outer / e-inner (A once per K-chunk, B L2-resident per XCD-pair);
// FETCH 42 MB and no-spill of this live-set shape verified in R4.
// R4 post-mortem: MfmaUtil 20.5%, Occupancy 11% -> stall-bound, not traffic.
// Fixes vs v5:
//  (1) mfma 16x16x32 with INDEPENDENT accumulation chains (m97's shape;
//      v5's 32x32 had one 4-deep dependent chain at distance 1).
//  (2) LDS 56->52 KB (bias from global in epilogue) -> 3 blocks/CU,
//      pinned by __launch_bounds__(256,3) (VGPR cap 170).
//  (3) oi-OUTER compute so only wf[2] (8 regs) is live, not wf[2][4] (32):
//      live set ~{acc 64, xf 32, wf 8, pp 4, cv 4} ~= 140 < 170.
//      Per oi-group the unrolled ti loop gives 4 independent 2-chains.
// Swizzle unchanged (R3/R4: 0 conflicts): slot s of row r holds chunk
// s ^ (r&7) ^ ((r>>3)&3), both sides. One __syncthreads per t.
// ---------------------------------------------------------------------------
__global__ __launch_bounds__(256, 3) void moe_gemm_kernel(
    const u16* __restrict__ xbf, const u16* __restrict__ wbf,
    const float* __restrict__ coeffsT, const float* __restrict__ ebias,
    float* __restrict__ out) {
  __shared__ __align__(16) u16 As[BM * BK];        // 16 KB (X, single buf)
  __shared__ __align__(16) u16 Bs[2][BN * BK];     // 32 KB (W, dbuf)
  __shared__ __align__(16) float cS[KE * BM];      // 4 KB  coeffs slice

  const int tid = threadIdx.x;
  const int wave = tid >> 6, lane = tid & 63;

  // XCD swizzle: b&7 = xcd; XCD-pair owns one n-column (B slice 1 MB, L2).
  const int b = blockIdx.x;
  const int xcd = b & 7, sq = b >> 3;           // sq in [0,64)
  const int m0 = ((xcd & 1) * 64 + sq) * BM;    // token base
  const int n0 = (xcd >> 1) * BN;               // dout base

  const int wt = (wave >> 1) * 64;   // wave's token offset: {0,64}
  const int wo = (wave & 1) * 64;    // wave's dout  offset: {0,64}

  const int lr = lane & 15, lq = lane >> 4;     // frag row / k-quad
  const int l31 = lane & 31, l5 = lane >> 5;    // prologue cS staging
  const int lrow = lane >> 3, l7 = lane & 7;    // staging row/chunk

  // read-side swizzle keys per 16-row block i (wo/wt multiples of 64 drop
  // out of (row>>3)&3): key[i] = (lr&7) ^ ((i*2 + (lr>>3)) & 3)
  int key[4];
#pragma unroll
  for (int i = 0; i < 4; ++i) key[i] = (lr & 7) ^ ((i * 2 + (lr >> 3)) & 3);

  // staging: GLOAD j covers rows wave*32+j*8..+8; source col pre-swizzled.
  // sc_j = (l7 ^ lrow ^ j)*8 = s0 ^ (j*8)  [(wave*4+j)&3 == j for j<4]
  const int s0 = (l7 ^ lrow) * 8;
  const u16* aRow = xbf + (size_t)(m0 + wave * 32 + lrow) * DIN;
  const u16* bRow = wbf + (size_t)(n0 + wave * 32 + lrow) * DIN;

  // ---- prologue staging: X_0, W_(h0,e0), coeffs slice ----
#pragma unroll
  for (int j = 0; j < 4; ++j)
    GLOAD_LDS16(aRow + (size_t)(j * 8) * DIN + (s0 ^ (j * 8)),
                &As[(wave * 32 + j * 8) * BK]);
#pragma unroll
  for (int j = 0; j < 4; ++j)
    GLOAD_LDS16(bRow + (size_t)(j * 8) * DIN + (s0 ^ (j * 8)),
                &Bs[0][(wave * 32 + j * 8) * BK]);
  // cS[e][i] = coeffsT[e][m0+i]; wave w covers e in {2w,2w+1}
  GLOAD_LDS16(coeffsT + (size_t)(wave * 2 + l5) * NTOK + m0 + l31 * 4,
              &cS[wave * 256]);
  __syncthreads();

  const f32x4 vz = {};
  f32x4 acc[4][4] = {};   // [oi][ti], 64 regs
  bf16x8 xf[4][2];        // X frags for chunk h: [ti][kh], 32 regs

  for (int h = 0; h < 8; ++h) {
#pragma unroll
    for (int e = 0; e < KE; ++e) {
      // ---- STAGE next W tile into Bs[(e+1)&1] ----
      if (e < 7 || h < 7) {
        const size_t off = (e < 7)
            ? (size_t)(e + 1) * ESTRIDE + (size_t)h * 64
            : (size_t)(h + 1) * 64;   // wraps to expert 0, chunk h+1
#pragma unroll
        for (int j = 0; j < 4; ++j)
          GLOAD_LDS16(bRow + (size_t)(j * 8) * DIN + (s0 ^ (j * 8)) + off,
                      &Bs[(e + 1) & 1][(wave * 32 + j * 8) * BK]);
      }
      // ---- STAGE X_{h+1} at e==1 (reads of As at e==0 barrier-separated)
      if (e == 1 && h < 7) {
#pragma unroll
        for (int j = 0; j < 4; ++j)
          GLOAD_LDS16(aRow + (size_t)(j * 8) * DIN + (s0 ^ (j * 8)) +
                          (size_t)(h + 1) * 64,
                      &As[(wave * 32 + j * 8) * BK]);
      }

      // ---- X fragments (chunk h) once per h ----
      if (e == 0) {
#pragma unroll
        for (int ti = 0; ti < 4; ++ti)
#pragma unroll
          for (int kh = 0; kh < 2; ++kh)
            xf[ti][kh] = *(const bf16x8*)
                &As[(wt + ti * 16 + lr) * BK + ((kh * 4 + lq) ^ key[ti]) * 8];
      }

      // per-token coefficient scalars (broadcast ds_reads)
      float cv[4];
#pragma unroll
      for (int ti = 0; ti < 4; ++ti) cv[ti] = cS[e * BM + wt + ti * 16 + lr];

      // ---- COMPUTE + FOLD, oi-outer (only wf[2] live: 8 regs).
      // Per oi: unrolled ti loop = 4 independent 2-deep MFMA chains. ----
      const u16* Bp = Bs[e & 1];
#pragma unroll
      for (int oi = 0; oi < 4; ++oi) {
        bf16x8 wf0 = *(const bf16x8*)
            &Bp[(wo + oi * 16 + lr) * BK + ((0 * 4 + lq) ^ key[oi]) * 8];
        bf16x8 wf1 = *(const bf16x8*)
            &Bp[(wo + oi * 16 + lr) * BK + ((1 * 4 + lq) ^ key[oi]) * 8];
#pragma unroll
        for (int ti = 0; ti < 4; ++ti) {
          f32x4 pp;
          pp = __builtin_amdgcn_mfma_f32_16x16x32_bf16(
              wf0, xf[ti][0], vz, 0, 0, 0);
          pp = __builtin_amdgcn_mfma_f32_16x16x32_bf16(
              wf1, xf[ti][1], pp, 0, 0, 0);
#pragma unroll
          for (int r = 0; r < 4; ++r)
            acc[oi][ti][r] += cv[ti] * pp[r];
        }
      }
      __syncthreads();   // Bs[e&1] reads done before t+1 overwrites it
    }
  }

  // ---- epilogue: bias fold  acc[o,tok] += Sum_e c[e][tok]*beta[e][o] ----
  // (ebias read from global: 16 KB, L2-hot, once)
#pragma unroll
  for (int e = 0; e < KE; ++e) {
    float cv[4];
#pragma unroll
    for (int ti = 0; ti < 4; ++ti) cv[ti] = cS[e * BM + wt + ti * 16 + lr];
#pragma unroll
    for (int oi = 0; oi < 4; ++oi) {
      const f32x4 bb =
          *(const f32x4*)&ebias[e * DOUT + n0 + wo + oi * 16 + lq * 4];
#pragma unroll
      for (int ti = 0; ti < 4; ++ti)
#pragma unroll
        for (int r = 0; r < 4; ++r)
          acc[oi][ti][r] += cv[ti] * bb[r];
    }
  }

  // ---- stores: D[o, tok] -> out[tok, o]; 16x16 C/D: col=lr(tok),
  // row=lq*4+r (o, contiguous) -> one f32x4 store per frag ----
#pragma unroll
  for (int ti = 0; ti < 4; ++ti) {
    const size_t rowbase = (size_t)(m0 + wt + ti * 16 + lr) * DOUT;
#pragma unroll
    for (int oi = 0; oi < 4; ++oi)
      *(f32x4*)&out[rowbase + n0 + wo + oi * 16 + lq * 4] = acc[oi][ti];
  }
}

// ---------------------------------------------------------------------------
extern "C" void kernel_launch(void* const* d_in, const int* in_sizes, int n_in,
                              void* d_out, int out_size, void* d_ws,
                              size_t ws_size, hipStream_t stream) {
  (void)in_sizes; (void)n_in; (void)out_size; (void)ws_size;
  const float* x  = (const float*)d_in[0];   // [4,4096,512]
  const float* ew = (const float*)d_in[1];   // [8,512,512]
  const float* eb = (const float*)d_in[2];   // [8,512]
  const float* mw = (const float*)d_in[3];   // [8,512]
  const float* mb = (const float*)d_in[4];   // [8]
  float* out = (float*)d_out;                // [4,4096,512]

  // workspace layout: xbf 16 MB | wbf 4 MB | coeffsT 0.5 MB  (~20.5 MB)
  u16* xbf = (u16*)d_ws;
  u16* wbf = (u16*)((char*)d_ws + (size_t)NTOK * DIN * 2);
  float* coeffsT =
      (float*)((char*)d_ws + (size_t)NTOK * DIN * 2 + (size_t)KE * DOUT * DIN * 2);

  hipLaunchKernelGGL(gate_kernel, dim3(GATE_BLOCKS), dim3(256), 0, stream,
                     x, mw, mb, xbf, coeffsT);
  hipLaunchKernelGGL(wcast_kernel, dim3(WCONV_BLOCKS), dim3(256), 0, stream,
                     ew, wbf);
  hipLaunchKernelGGL(moe_gemm_kernel, dim3(512), dim3(256),
                     0, stream, xbf, wbf, coeffsT, eb, out);
}

// Round 8
// 391.802 us; speedup vs baseline: 2.8429x; 2.8429x over previous
//
#include <hip/hip_runtime.h>
#include <stdint.h>

#define NTOK 16384   // B*S = 4*4096
#define DIN 512
#define DOUT 512
#define KE 8
#define BM 128
#define BN 128
#define BK 64
#define ESTRIDE (DOUT * DIN)

#define GATE_BLOCKS 4096           // 1 token/wave, 4 waves/block
#define WCONV_BLOCKS 1024          // 2M elements / (256*8)

typedef unsigned short u16;
typedef u16 u16x8 __attribute__((ext_vector_type(8)));
typedef __bf16 bf16x8 __attribute__((ext_vector_type(8)));
typedef float f32x4 __attribute__((ext_vector_type(4)));

__device__ __forceinline__ u16 f2bf(float f) {
  union { float f; unsigned u; } v; v.f = f;
  unsigned r = v.u + 0x7FFFu + ((v.u >> 16) & 1u);   // RNE; inputs are finite
  return (u16)(r >> 16);
}

// async global->LDS, 16B per lane; LDS dest is wave-uniform base + lane*16
#define GLOAD_LDS16(gp, lp)                                              \
  __builtin_amdgcn_global_load_lds(                                     \
      (__attribute__((address_space(1))) void*)(gp),                    \
      (__attribute__((address_space(3))) void*)(lp), 16, 0, 0)

// ---------------------------------------------------------------------------
// Kernel 1a: gating softmax + x fp32->bf16 cast. One token per wave.
// Coeffs written TRANSPOSED: coeffsT[e][tok].
// ---------------------------------------------------------------------------
__global__ __launch_bounds__(256) void gate_kernel(
    const float* __restrict__ x, const float* __restrict__ mw,
    const float* __restrict__ mb, u16* __restrict__ xbf,
    float* __restrict__ coeffsT) {
  const int tid = threadIdx.x;
  const int wave = tid >> 6, lane = tid & 63;
  const int tok = blockIdx.x * 4 + wave;

  // mixer weight slice for this lane, in registers (broadcast loads)
  float mwr[KE][8];
#pragma unroll
  for (int k = 0; k < KE; ++k) {
    const float* wr = &mw[k * DIN + lane * 8];
    const float4 w0 = *(const float4*)wr;
    const float4 w1 = *(const float4*)(wr + 4);
    mwr[k][0] = w0.x; mwr[k][1] = w0.y; mwr[k][2] = w0.z; mwr[k][3] = w0.w;
    mwr[k][4] = w1.x; mwr[k][5] = w1.y; mwr[k][6] = w1.z; mwr[k][7] = w1.w;
  }
  float mbr[KE];
#pragma unroll
  for (int k = 0; k < KE; ++k) mbr[k] = mb[k];

  const float* xr = x + (size_t)tok * DIN + lane * 8;
  const float4 xa = *(const float4*)xr;
  const float4 xb = *(const float4*)(xr + 4);

  u16x8 p;
  p[0] = f2bf(xa.x); p[1] = f2bf(xa.y); p[2] = f2bf(xa.z); p[3] = f2bf(xa.w);
  p[4] = f2bf(xb.x); p[5] = f2bf(xb.y); p[6] = f2bf(xb.z); p[7] = f2bf(xb.w);
  *(u16x8*)(xbf + (size_t)tok * DIN + lane * 8) = p;

  float lg[KE];
#pragma unroll
  for (int k = 0; k < KE; ++k) {
    lg[k] = xa.x * mwr[k][0] + xa.y * mwr[k][1] + xa.z * mwr[k][2] +
            xa.w * mwr[k][3] + xb.x * mwr[k][4] + xb.y * mwr[k][5] +
            xb.z * mwr[k][6] + xb.w * mwr[k][7];
  }
#pragma unroll
  for (int off = 32; off; off >>= 1)
#pragma unroll
    for (int k = 0; k < KE; ++k) lg[k] += __shfl_xor(lg[k], off);

#pragma unroll
  for (int k = 0; k < KE; ++k) lg[k] += mbr[k];
  float mx = lg[0];
#pragma unroll
  for (int k = 1; k < KE; ++k) mx = fmaxf(mx, lg[k]);
  float s = 0.f;
#pragma unroll
  for (int k = 0; k < KE; ++k) { lg[k] = __expf(lg[k] - mx); s += lg[k]; }
  const float inv = 1.f / s;
  if (lane == 0) {
#pragma unroll
    for (int k = 0; k < KE; ++k) coeffsT[(size_t)k * NTOK + tok] = lg[k] * inv;
  }
}

// ---------------------------------------------------------------------------
// Kernel 1b: expert-weight fp32->bf16 cast (8 elements/thread).
// ---------------------------------------------------------------------------
__global__ __launch_bounds__(256) void wcast_kernel(
    const float* __restrict__ ew, u16* __restrict__ wbf) {
  const size_t i = ((size_t)blockIdx.x * 256 + threadIdx.x) * 8;
  const float4 a = *(const float4*)&ew[i];
  const float4 b = *(const float4*)&ew[i + 4];
  u16x8 p;
  p[0] = f2bf(a.x); p[1] = f2bf(a.y); p[2] = f2bf(a.z); p[3] = f2bf(a.w);
  p[4] = f2bf(b.x); p[5] = f2bf(b.y); p[6] = f2bf(b.z); p[7] = f2bf(b.w);
  *(u16x8*)&wbf[i] = p;
}

// ---------------------------------------------------------------------------
// Kernel 2: MoE GEMM v8 = v7 with the occupancy pin REMOVED.
// R7 post-mortem: __launch_bounds__(256,3) capped the unified file at
// ~168 regs -> allocator split ~84 VGPR + AGPR and SPILLED the fold's
// live set in the t-loop (VGPR_Count 84, WRITE 1.98 GB scratch). Rule:
// with >=100 live regs, never pin min-occupancy; LDS sets residency.
// LDS 52 KB already gives 3 blocks/CU; unpinned alloc ~160 regs (R4-
// verified live-set shape) still allows 3 waves/SIMD (512/160=3.2).
// Kept from v7 (unmeasured, rationale stands):
//  (1) mfma 16x16x32, 4 independent 2-deep chains per oi-group
//      (v5's 32x32 dependent chain at distance 1 stalled the pipe).
//  (2) oi-outer compute: only wf[2] (8 regs) live, pp 4 regs.
//  (3) h-outer / e-inner: A staged once per K-chunk (FETCH 42 MB, R4),
//      B streams L2-resident per XCD-pair.
//  (4) bias in epilogue from global (LDS 56->52 KB).
// Swizzle (R3/R4: 0 conflicts): slot s of row r holds chunk
// s ^ (r&7) ^ ((r>>3)&3), both sides. One __syncthreads per t.
// ---------------------------------------------------------------------------
__global__ __launch_bounds__(256) void moe_gemm_kernel(
    const u16* __restrict__ xbf, const u16* __restrict__ wbf,
    const float* __restrict__ coeffsT, const float* __restrict__ ebias,
    float* __restrict__ out) {
  __shared__ __align__(16) u16 As[BM * BK];        // 16 KB (X, single buf)
  __shared__ __align__(16) u16 Bs[2][BN * BK];     // 32 KB (W, dbuf)
  __shared__ __align__(16) float cS[KE * BM];      // 4 KB  coeffs slice

  const int tid = threadIdx.x;
  const int wave = tid >> 6, lane = tid & 63;

  // XCD swizzle: b&7 = xcd; XCD-pair owns one n-column (B slice 1 MB, L2).
  const int b = blockIdx.x;
  const int xcd = b & 7, sq = b >> 3;           // sq in [0,64)
  const int m0 = ((xcd & 1) * 64 + sq) * BM;    // token base
  const int n0 = (xcd >> 1) * BN;               // dout base

  const int wt = (wave >> 1) * 64;   // wave's token offset: {0,64}
  const int wo = (wave & 1) * 64;    // wave's dout  offset: {0,64}

  const int lr = lane & 15, lq = lane >> 4;     // frag row / k-quad
  const int l31 = lane & 31, l5 = lane >> 5;    // prologue cS staging
  const int lrow = lane >> 3, l7 = lane & 7;    // staging row/chunk

  // read-side swizzle keys per 16-row block i (wo/wt multiples of 64 drop
  // out of (row>>3)&3): key[i] = (lr&7) ^ ((i*2 + (lr>>3)) & 3)
  int key[4];
#pragma unroll
  for (int i = 0; i < 4; ++i) key[i] = (lr & 7) ^ ((i * 2 + (lr >> 3)) & 3);

  // staging: GLOAD j covers rows wave*32+j*8..+8; source col pre-swizzled.
  // sc_j = (l7 ^ lrow ^ j)*8 = s0 ^ (j*8)  [(wave*4+j)&3 == j for j<4]
  const int s0 = (l7 ^ lrow) * 8;
  const u16* aRow = xbf + (size_t)(m0 + wave * 32 + lrow) * DIN;
  const u16* bRow = wbf + (size_t)(n0 + wave * 32 + lrow) * DIN;

  // ---- prologue staging: X_0, W_(h0,e0), coeffs slice ----
#pragma unroll
  for (int j = 0; j < 4; ++j)
    GLOAD_LDS16(aRow + (size_t)(j * 8) * DIN + (s0 ^ (j * 8)),
                &As[(wave * 32 + j * 8) * BK]);
#pragma unroll
  for (int j = 0; j < 4; ++j)
    GLOAD_LDS16(bRow + (size_t)(j * 8) * DIN + (s0 ^ (j * 8)),
                &Bs[0][(wave * 32 + j * 8) * BK]);
  // cS[e][i] = coeffsT[e][m0+i]; wave w covers e in {2w,2w+1}
  GLOAD_LDS16(coeffsT + (size_t)(wave * 2 + l5) * NTOK + m0 + l31 * 4,
              &cS[wave * 256]);
  __syncthreads();

  const f32x4 vz = {};
  f32x4 acc[4][4] = {};   // [oi][ti], 64 regs
  bf16x8 xf[4][2];        // X frags for chunk h: [ti][kh], 32 regs

  for (int h = 0; h < 8; ++h) {
#pragma unroll
    for (int e = 0; e < KE; ++e) {
      // ---- STAGE next W tile into Bs[(e+1)&1] ----
      if (e < 7 || h < 7) {
        const size_t off = (e < 7)
            ? (size_t)(e + 1) * ESTRIDE + (size_t)h * 64
            : (size_t)(h + 1) * 64;   // wraps to expert 0, chunk h+1
#pragma unroll
        for (int j = 0; j < 4; ++j)
          GLOAD_LDS16(bRow + (size_t)(j * 8) * DIN + (s0 ^ (j * 8)) + off,
                      &Bs[(e + 1) & 1][(wave * 32 + j * 8) * BK]);
      }
      // ---- STAGE X_{h+1} at e==1 (reads of As at e==0 barrier-separated)
      if (e == 1 && h < 7) {
#pragma unroll
        for (int j = 0; j < 4; ++j)
          GLOAD_LDS16(aRow + (size_t)(j * 8) * DIN + (s0 ^ (j * 8)) +
                          (size_t)(h + 1) * 64,
                      &As[(wave * 32 + j * 8) * BK]);
      }

      // ---- X fragments (chunk h) once per h ----
      if (e == 0) {
#pragma unroll
        for (int ti = 0; ti < 4; ++ti)
#pragma unroll
          for (int kh = 0; kh < 2; ++kh)
            xf[ti][kh] = *(const bf16x8*)
                &As[(wt + ti * 16 + lr) * BK + ((kh * 4 + lq) ^ key[ti]) * 8];
      }

      // per-token coefficient scalars (broadcast ds_reads)
      float cv[4];
#pragma unroll
      for (int ti = 0; ti < 4; ++ti) cv[ti] = cS[e * BM + wt + ti * 16 + lr];

      // ---- COMPUTE + FOLD, oi-outer (only wf[2] live: 8 regs).
      // Per oi: unrolled ti loop = 4 independent 2-deep MFMA chains. ----
      const u16* Bp = Bs[e & 1];
#pragma unroll
      for (int oi = 0; oi < 4; ++oi) {
        bf16x8 wf0 = *(const bf16x8*)
            &Bp[(wo + oi * 16 + lr) * BK + ((0 * 4 + lq) ^ key[oi]) * 8];
        bf16x8 wf1 = *(const bf16x8*)
            &Bp[(wo + oi * 16 + lr) * BK + ((1 * 4 + lq) ^ key[oi]) * 8];
#pragma unroll
        for (int ti = 0; ti < 4; ++ti) {
          f32x4 pp;
          pp = __builtin_amdgcn_mfma_f32_16x16x32_bf16(
              wf0, xf[ti][0], vz, 0, 0, 0);
          pp = __builtin_amdgcn_mfma_f32_16x16x32_bf16(
              wf1, xf[ti][1], pp, 0, 0, 0);
#pragma unroll
          for (int r = 0; r < 4; ++r)
            acc[oi][ti][r] += cv[ti] * pp[r];
        }
      }
      __syncthreads();   // Bs[e&1] reads done before t+1 overwrites it
    }
  }

  // ---- epilogue: bias fold  acc[o,tok] += Sum_e c[e][tok]*beta[e][o] ----
  // (ebias read from global: 16 KB, L2-hot, once)
#pragma unroll
  for (int e = 0; e < KE; ++e) {
    float cv[4];
#pragma unroll
    for (int ti = 0; ti < 4; ++ti) cv[ti] = cS[e * BM + wt + ti * 16 + lr];
#pragma unroll
    for (int oi = 0; oi < 4; ++oi) {
      const f32x4 bb =
          *(const f32x4*)&ebias[e * DOUT + n0 + wo + oi * 16 + lq * 4];
#pragma unroll
      for (int ti = 0; ti < 4; ++ti)
#pragma unroll
        for (int r = 0; r < 4; ++r)
          acc[oi][ti][r] += cv[ti] * bb[r];
    }
  }

  // ---- stores: D[o, tok] -> out[tok, o]; 16x16 C/D: col=lr(tok),
  // row=lq*4+r (o, contiguous) -> one f32x4 store per frag ----
#pragma unroll
  for (int ti = 0; ti < 4; ++ti) {
    const size_t rowbase = (size_t)(m0 + wt + ti * 16 + lr) * DOUT;
#pragma unroll
    for (int oi = 0; oi < 4; ++oi)
      *(f32x4*)&out[rowbase + n0 + wo + oi * 16 + lq * 4] = acc[oi][ti];
  }
}

// ---------------------------------------------------------------------------
extern "C" void kernel_launch(void* const* d_in, const int* in_sizes, int n_in,
                              void* d_out, int out_size, void* d_ws,
                              size_t ws_size, hipStream_t stream) {
  (void)in_sizes; (void)n_in; (void)out_size; (void)ws_size;
  const float* x  = (const float*)d_in[0];   // [4,4096,512]
  const float* ew = (const float*)d_in[1];   // [8,512,512]
  const float* eb = (const float*)d_in[2];   // [8,512]
  const float* mw = (const float*)d_in[3];   // [8,512]
  const float* mb = (const float*)d_in[4];   // [8]
  float* out = (float*)d_out;                // [4,4096,512]

  // workspace layout: xbf 16 MB | wbf 4 MB | coeffsT 0.5 MB  (~20.5 MB)
  u16* xbf = (u16*)d_ws;
  u16* wbf = (u16*)((char*)d_ws + (size_t)NTOK * DIN * 2);
  float* coeffsT =
      (float*)((char*)d_ws + (size_t)NTOK * DIN * 2 + (size_t)KE * DOUT * DIN * 2);

  hipLaunchKernelGGL(gate_kernel, dim3(GATE_BLOCKS), dim3(256), 0, stream,
                     x, mw, mb, xbf, coeffsT);
  hipLaunchKernelGGL(wcast_kernel, dim3(WCONV_BLOCKS), dim3(256), 0, stream,
                     ew, wbf);
  hipLaunchKernelGGL(moe_gemm_kernel, dim3(512), dim3(256),
                     0, stream, xbf, wbf, coeffsT, eb, out);
}

// Round 9
// 224.802 us; speedup vs baseline: 4.9548x; 1.7429x over previous
//
#include <hip/hip_runtime.h>
#include <stdint.h>

#define NTOK 16384   // B*S = 4*4096
#define DIN 512
#define DOUT 512
#define KE 8
#define BM 128
#define BN 128
#define BK 64
#define ESTRIDE (DOUT * DIN)

#define GATE_BLOCKS 4096           // 1 token/wave, 4 waves/block
#define WCONV_BLOCKS 1024          // 2M elements / (256*8)

typedef unsigned short u16;
typedef u16 u16x8 __attribute__((ext_vector_type(8)));
typedef __bf16 bf16x8 __attribute__((ext_vector_type(8)));
typedef float f32x4 __attribute__((ext_vector_type(4)));

__device__ __forceinline__ u16 f2bf(float f) {
  union { float f; unsigned u; } v; v.f = f;
  unsigned r = v.u + 0x7FFFu + ((v.u >> 16) & 1u);   // RNE; inputs are finite
  return (u16)(r >> 16);
}

// async global->LDS, 16B per lane; LDS dest is wave-uniform base + lane*16
#define GLOAD_LDS16(gp, lp)                                              \
  __builtin_amdgcn_global_load_lds(                                     \
      (__attribute__((address_space(1))) void*)(gp),                    \
      (__attribute__((address_space(3))) void*)(lp), 16, 0, 0)

// ---------------------------------------------------------------------------
// Kernel 1a: gating softmax + x fp32->bf16 cast. One token per wave.
// Coeffs written TRANSPOSED: coeffsT[e][tok].
// ---------------------------------------------------------------------------
__global__ __launch_bounds__(256) void gate_kernel(
    const float* __restrict__ x, const float* __restrict__ mw,
    const float* __restrict__ mb, u16* __restrict__ xbf,
    float* __restrict__ coeffsT) {
  const int tid = threadIdx.x;
  const int wave = tid >> 6, lane = tid & 63;
  const int tok = blockIdx.x * 4 + wave;

  // mixer weight slice for this lane, in registers (broadcast loads)
  float mwr[KE][8];
#pragma unroll
  for (int k = 0; k < KE; ++k) {
    const float* wr = &mw[k * DIN + lane * 8];
    const float4 w0 = *(const float4*)wr;
    const float4 w1 = *(const float4*)(wr + 4);
    mwr[k][0] = w0.x; mwr[k][1] = w0.y; mwr[k][2] = w0.z; mwr[k][3] = w0.w;
    mwr[k][4] = w1.x; mwr[k][5] = w1.y; mwr[k][6] = w1.z; mwr[k][7] = w1.w;
  }
  float mbr[KE];
#pragma unroll
  for (int k = 0; k < KE; ++k) mbr[k] = mb[k];

  const float* xr = x + (size_t)tok * DIN + lane * 8;
  const float4 xa = *(const float4*)xr;
  const float4 xb = *(const float4*)(xr + 4);

  u16x8 p;
  p[0] = f2bf(xa.x); p[1] = f2bf(xa.y); p[2] = f2bf(xa.z); p[3] = f2bf(xa.w);
  p[4] = f2bf(xb.x); p[5] = f2bf(xb.y); p[6] = f2bf(xb.z); p[7] = f2bf(xb.w);
  *(u16x8*)(xbf + (size_t)tok * DIN + lane * 8) = p;

  float lg[KE];
#pragma unroll
  for (int k = 0; k < KE; ++k) {
    lg[k] = xa.x * mwr[k][0] + xa.y * mwr[k][1] + xa.z * mwr[k][2] +
            xa.w * mwr[k][3] + xb.x * mwr[k][4] + xb.y * mwr[k][5] +
            xb.z * mwr[k][6] + xb.w * mwr[k][7];
  }
#pragma unroll
  for (int off = 32; off; off >>= 1)
#pragma unroll
    for (int k = 0; k < KE; ++k) lg[k] += __shfl_xor(lg[k], off);

#pragma unroll
  for (int k = 0; k < KE; ++k) lg[k] += mbr[k];
  float mx = lg[0];
#pragma unroll
  for (int k = 1; k < KE; ++k) mx = fmaxf(mx, lg[k]);
  float s = 0.f;
#pragma unroll
  for (int k = 0; k < KE; ++k) { lg[k] = __expf(lg[k] - mx); s += lg[k]; }
  const float inv = 1.f / s;
  if (lane == 0) {
#pragma unroll
    for (int k = 0; k < KE; ++k) coeffsT[(size_t)k * NTOK + tok] = lg[k] * inv;
  }
}

// ---------------------------------------------------------------------------
// Kernel 1b: expert-weight fp32->bf16 cast (8 elements/thread).
// ---------------------------------------------------------------------------
__global__ __launch_bounds__(256) void wcast_kernel(
    const float* __restrict__ ew, u16* __restrict__ wbf) {
  const size_t i = ((size_t)blockIdx.x * 256 + threadIdx.x) * 8;
  const float4 a = *(const float4*)&ew[i];
  const float4 b = *(const float4*)&ew[i + 4];
  u16x8 p;
  p[0] = f2bf(a.x); p[1] = f2bf(a.y); p[2] = f2bf(a.z); p[3] = f2bf(a.w);
  p[4] = f2bf(b.x); p[5] = f2bf(b.y); p[6] = f2bf(b.z); p[7] = f2bf(b.w);
  *(u16x8*)&wbf[i] = p;
}

// ---------------------------------------------------------------------------
// Kernel 2: MoE GEMM v9 = v8 with e-loop unroll reverted to 2 (h pinned 1).
// R8 post-mortem: even unpinned, VGPR_Count=256 AND 530 MB scratch WRITE
// -> the FULL e-unroll (8x straight-line body, 40 global_load_lds) let
// the scheduler software-pipeline staging across the whole body, hoisting
// address/fragment live ranges -> pressure explosion. R4's clean build
// (VGPR 160, 0 spill, 0 conflicts) used #pragma unroll 2 -- restored here.
// SQ_LDS_BANK_CONFLICT was bit-identical (4718592) in the three spilling
// kernels (R2/R7/R8) and 0 in R4: conflicts are a spill artifact, not the
// read pattern (16-row frag reads hit all 32 banks once per 8-lane group).
// Kept from v8: 16x16x32 mfma, 4 independent 2-deep chains per oi-group;
// oi-outer compute (wf[2]=8 regs live); h-outer/e-inner (A once/chunk,
// B L2-resident per XCD-pair); bias in epilogue; 52 KB LDS (3 blk/CU);
// swizzle slot s of row r = chunk s^(r&7)^((r>>3)&3) both sides;
// one __syncthreads per t; __launch_bounds__(256) unpinned (R7 lesson).
// ---------------------------------------------------------------------------
__global__ __launch_bounds__(256) void moe_gemm_kernel(
    const u16* __restrict__ xbf, const u16* __restrict__ wbf,
    const float* __restrict__ coeffsT, const float* __restrict__ ebias,
    float* __restrict__ out) {
  __shared__ __align__(16) u16 As[BM * BK];        // 16 KB (X, single buf)
  __shared__ __align__(16) u16 Bs[2][BN * BK];     // 32 KB (W, dbuf)
  __shared__ __align__(16) float cS[KE * BM];      // 4 KB  coeffs slice

  const int tid = threadIdx.x;
  const int wave = tid >> 6, lane = tid & 63;

  // XCD swizzle: b&7 = xcd; XCD-pair owns one n-column (B slice 1 MB, L2).
  const int b = blockIdx.x;
  const int xcd = b & 7, sq = b >> 3;           // sq in [0,64)
  const int m0 = ((xcd & 1) * 64 + sq) * BM;    // token base
  const int n0 = (xcd >> 1) * BN;               // dout base

  const int wt = (wave >> 1) * 64;   // wave's token offset: {0,64}
  const int wo = (wave & 1) * 64;    // wave's dout  offset: {0,64}

  const int lr = lane & 15, lq = lane >> 4;     // frag row / k-quad
  const int l31 = lane & 31, l5 = lane >> 5;    // prologue cS staging
  const int lrow = lane >> 3, l7 = lane & 7;    // staging row/chunk

  // read-side swizzle keys per 16-row block i (wo/wt multiples of 64 drop
  // out of (row>>3)&3): key[i] = (lr&7) ^ ((i*2 + (lr>>3)) & 3)
  int key[4];
#pragma unroll
  for (int i = 0; i < 4; ++i) key[i] = (lr & 7) ^ ((i * 2 + (lr >> 3)) & 3);

  // staging: GLOAD j covers rows wave*32+j*8..+8; source col pre-swizzled.
  // sc_j = (l7 ^ lrow ^ j)*8 = s0 ^ (j*8)  [(wave*4+j)&3 == j for j<4]
  const int s0 = (l7 ^ lrow) * 8;
  const u16* aRow = xbf + (size_t)(m0 + wave * 32 + lrow) * DIN;
  const u16* bRow = wbf + (size_t)(n0 + wave * 32 + lrow) * DIN;

  // ---- prologue staging: X_0, W_(h0,e0), coeffs slice ----
#pragma unroll
  for (int j = 0; j < 4; ++j)
    GLOAD_LDS16(aRow + (size_t)(j * 8) * DIN + (s0 ^ (j * 8)),
                &As[(wave * 32 + j * 8) * BK]);
#pragma unroll
  for (int j = 0; j < 4; ++j)
    GLOAD_LDS16(bRow + (size_t)(j * 8) * DIN + (s0 ^ (j * 8)),
                &Bs[0][(wave * 32 + j * 8) * BK]);
  // cS[e][i] = coeffsT[e][m0+i]; wave w covers e in {2w,2w+1}
  GLOAD_LDS16(coeffsT + (size_t)(wave * 2 + l5) * NTOK + m0 + l31 * 4,
              &cS[wave * 256]);
  __syncthreads();

  const f32x4 vz = {};
  f32x4 acc[4][4] = {};   // [oi][ti], 64 regs
  bf16x8 xf[4][2];        // X frags for chunk h: [ti][kh], 32 regs

#pragma unroll 1
  for (int h = 0; h < 8; ++h) {
#pragma unroll 2
    for (int e = 0; e < KE; ++e) {
      // ---- STAGE next W tile into Bs[(e+1)&1] ----
      if (e < 7 || h < 7) {
        const size_t off = (e < 7)
            ? (size_t)(e + 1) * ESTRIDE + (size_t)h * 64
            : (size_t)(h + 1) * 64;   // wraps to expert 0, chunk h+1
#pragma unroll
        for (int j = 0; j < 4; ++j)
          GLOAD_LDS16(bRow + (size_t)(j * 8) * DIN + (s0 ^ (j * 8)) + off,
                      &Bs[(e + 1) & 1][(wave * 32 + j * 8) * BK]);
      }
      // ---- STAGE X_{h+1} at e==1 (reads of As at e==0 barrier-separated)
      if (e == 1 && h < 7) {
#pragma unroll
        for (int j = 0; j < 4; ++j)
          GLOAD_LDS16(aRow + (size_t)(j * 8) * DIN + (s0 ^ (j * 8)) +
                          (size_t)(h + 1) * 64,
                      &As[(wave * 32 + j * 8) * BK]);
      }

      // ---- X fragments (chunk h) once per h ----
      if (e == 0) {
#pragma unroll
        for (int ti = 0; ti < 4; ++ti)
#pragma unroll
          for (int kh = 0; kh < 2; ++kh)
            xf[ti][kh] = *(const bf16x8*)
                &As[(wt + ti * 16 + lr) * BK + ((kh * 4 + lq) ^ key[ti]) * 8];
      }

      // per-token coefficient scalars (broadcast ds_reads)
      float cv[4];
#pragma unroll
      for (int ti = 0; ti < 4; ++ti) cv[ti] = cS[e * BM + wt + ti * 16 + lr];

      // ---- COMPUTE + FOLD, oi-outer (only wf[2] live: 8 regs).
      // Per oi: unrolled ti loop = 4 independent 2-deep MFMA chains. ----
      const u16* Bp = Bs[e & 1];
#pragma unroll
      for (int oi = 0; oi < 4; ++oi) {
        bf16x8 wf0 = *(const bf16x8*)
            &Bp[(wo + oi * 16 + lr) * BK + ((0 * 4 + lq) ^ key[oi]) * 8];
        bf16x8 wf1 = *(const bf16x8*)
            &Bp[(wo + oi * 16 + lr) * BK + ((1 * 4 + lq) ^ key[oi]) * 8];
#pragma unroll
        for (int ti = 0; ti < 4; ++ti) {
          f32x4 pp;
          pp = __builtin_amdgcn_mfma_f32_16x16x32_bf16(
              wf0, xf[ti][0], vz, 0, 0, 0);
          pp = __builtin_amdgcn_mfma_f32_16x16x32_bf16(
              wf1, xf[ti][1], pp, 0, 0, 0);
#pragma unroll
          for (int r = 0; r < 4; ++r)
            acc[oi][ti][r] += cv[ti] * pp[r];
        }
      }
      __syncthreads();   // Bs[e&1] reads done before t+1 overwrites it
    }
  }

  // ---- epilogue: bias fold  acc[o,tok] += Sum_e c[e][tok]*beta[e][o] ----
  // (ebias read from global: 16 KB, L2-hot, once)
#pragma unroll
  for (int e = 0; e < KE; ++e) {
    float cv[4];
#pragma unroll
    for (int ti = 0; ti < 4; ++ti) cv[ti] = cS[e * BM + wt + ti * 16 + lr];
#pragma unroll
    for (int oi = 0; oi < 4; ++oi) {
      const f32x4 bb =
          *(const f32x4*)&ebias[e * DOUT + n0 + wo + oi * 16 + lq * 4];
#pragma unroll
      for (int ti = 0; ti < 4; ++ti)
#pragma unroll
        for (int r = 0; r < 4; ++r)
          acc[oi][ti][r] += cv[ti] * bb[r];
    }
  }

  // ---- stores: D[o, tok] -> out[tok, o]; 16x16 C/D: col=lr(tok),
  // row=lq*4+r (o, contiguous) -> one f32x4 store per frag ----
#pragma unroll
  for (int ti = 0; ti < 4; ++ti) {
    const size_t rowbase = (size_t)(m0 + wt + ti * 16 + lr) * DOUT;
#pragma unroll
    for (int oi = 0; oi < 4; ++oi)
      *(f32x4*)&out[rowbase + n0 + wo + oi * 16 + lq * 4] = acc[oi][ti];
  }
}

// ---------------------------------------------------------------------------
extern "C" void kernel_launch(void* const* d_in, const int* in_sizes, int n_in,
                              void* d_out, int out_size, void* d_ws,
                              size_t ws_size, hipStream_t stream) {
  (void)in_sizes; (void)n_in; (void)out_size; (void)ws_size;
  const float* x  = (const float*)d_in[0];   // [4,4096,512]
  const float* ew = (const float*)d_in[1];   // [8,512,512]
  const float* eb = (const float*)d_in[2];   // [8,512]
  const float* mw = (const float*)d_in[3];   // [8,512]
  const float* mb = (const float*)d_in[4];   // [8]
  float* out = (float*)d_out;                // [4,4096,512]

  // workspace layout: xbf 16 MB | wbf 4 MB | coeffsT 0.5 MB  (~20.5 MB)
  u16* xbf = (u16*)d_ws;
  u16* wbf = (u16*)((char*)d_ws + (size_t)NTOK * DIN * 2);
  float* coeffsT =
      (float*)((char*)d_ws + (size_t)NTOK * DIN * 2 + (size_t)KE * DOUT * DIN * 2);

  hipLaunchKernelGGL(gate_kernel, dim3(GATE_BLOCKS), dim3(256), 0, stream,
                     x, mw, mb, xbf, coeffsT);
  hipLaunchKernelGGL(wcast_kernel, dim3(WCONV_BLOCKS), dim3(256), 0, stream,
                     ew, wbf);
  hipLaunchKernelGGL(moe_gemm_kernel, dim3(512), dim3(256),
                     0, stream, xbf, wbf, coeffsT, eb, out);
}

// Round 10
// 196.115 us; speedup vs baseline: 5.6796x; 1.1463x over previous
//
#include <hip/hip_runtime.h>
#include <stdint.h>

#define NTOK 16384   // B*S = 4*4096
#define DIN 512
#define DOUT 512
#define KE 8
#define BM 128
#define BN 64
#define BK 64
#define ESTRIDE (DOUT * DIN)

#define GATE_BLOCKS 4096           // 1 token/wave, 4 waves/block
#define WCONV_BLOCKS 1024          // 2M elements / (256*8)

typedef unsigned short u16;
typedef u16 u16x8 __attribute__((ext_vector_type(8)));
typedef __bf16 bf16x8 __attribute__((ext_vector_type(8)));
typedef float f32x4 __attribute__((ext_vector_type(4)));

__device__ __forceinline__ u16 f2bf(float f) {
  union { float f; unsigned u; } v; v.f = f;
  unsigned r = v.u + 0x7FFFu + ((v.u >> 16) & 1u);   // RNE; inputs are finite
  return (u16)(r >> 16);
}

// async global->LDS, 16B per lane; LDS dest is wave-uniform base + lane*16
#define GLOAD_LDS16(gp, lp)                                              \
  __builtin_amdgcn_global_load_lds(                                     \
      (__attribute__((address_space(1))) void*)(gp),                    \
      (__attribute__((address_space(3))) void*)(lp), 16, 0, 0)

// ---------------------------------------------------------------------------
// Kernel 1a: gating softmax + x fp32->bf16 cast. One token per wave.
// Coeffs written TRANSPOSED: coeffsT[e][tok].
// ---------------------------------------------------------------------------
__global__ __launch_bounds__(256) void gate_kernel(
    const float* __restrict__ x, const float* __restrict__ mw,
    const float* __restrict__ mb, u16* __restrict__ xbf,
    float* __restrict__ coeffsT) {
  const int tid = threadIdx.x;
  const int wave = tid >> 6, lane = tid & 63;
  const int tok = blockIdx.x * 4 + wave;

  // mixer weight slice for this lane, in registers (broadcast loads)
  float mwr[KE][8];
#pragma unroll
  for (int k = 0; k < KE; ++k) {
    const float* wr = &mw[k * DIN + lane * 8];
    const float4 w0 = *(const float4*)wr;
    const float4 w1 = *(const float4*)(wr + 4);
    mwr[k][0] = w0.x; mwr[k][1] = w0.y; mwr[k][2] = w0.z; mwr[k][3] = w0.w;
    mwr[k][4] = w1.x; mwr[k][5] = w1.y; mwr[k][6] = w1.z; mwr[k][7] = w1.w;
  }
  float mbr[KE];
#pragma unroll
  for (int k = 0; k < KE; ++k) mbr[k] = mb[k];

  const float* xr = x + (size_t)tok * DIN + lane * 8;
  const float4 xa = *(const float4*)xr;
  const float4 xb = *(const float4*)(xr + 4);

  u16x8 p;
  p[0] = f2bf(xa.x); p[1] = f2bf(xa.y); p[2] = f2bf(xa.z); p[3] = f2bf(xa.w);
  p[4] = f2bf(xb.x); p[5] = f2bf(xb.y); p[6] = f2bf(xb.z); p[7] = f2bf(xb.w);
  *(u16x8*)(xbf + (size_t)tok * DIN + lane * 8) = p;

  float lg[KE];
#pragma unroll
  for (int k = 0; k < KE; ++k) {
    lg[k] = xa.x * mwr[k][0] + xa.y * mwr[k][1] + xa.z * mwr[k][2] +
            xa.w * mwr[k][3] + xb.x * mwr[k][4] + xb.y * mwr[k][5] +
            xb.z * mwr[k][6] + xb.w * mwr[k][7];
  }
#pragma unroll
  for (int off = 32; off; off >>= 1)
#pragma unroll
    for (int k = 0; k < KE; ++k) lg[k] += __shfl_xor(lg[k], off);

#pragma unroll
  for (int k = 0; k < KE; ++k) lg[k] += mbr[k];
  float mx = lg[0];
#pragma unroll
  for (int k = 1; k < KE; ++k) mx = fmaxf(mx, lg[k]);
  float s = 0.f;
#pragma unroll
  for (int k = 0; k < KE; ++k) { lg[k] = __expf(lg[k] - mx); s += lg[k]; }
  const float inv = 1.f / s;
  if (lane == 0) {
#pragma unroll
    for (int k = 0; k < KE; ++k) coeffsT[(size_t)k * NTOK + tok] = lg[k] * inv;
  }
}

// ---------------------------------------------------------------------------
// Kernel 1b: expert-weight fp32->bf16 cast (8 elements/thread).
// ---------------------------------------------------------------------------
__global__ __launch_bounds__(256) void wcast_kernel(
    const float* __restrict__ ew, u16* __restrict__ wbf) {
  const size_t i = ((size_t)blockIdx.x * 256 + threadIdx.x) * 8;
  const float4 a = *(const float4*)&ew[i];
  const float4 b = *(const float4*)&ew[i + 4];
  u16x8 p;
  p[0] = f2bf(a.x); p[1] = f2bf(a.y); p[2] = f2bf(a.z); p[3] = f2bf(a.w);
  p[4] = f2bf(b.x); p[5] = f2bf(b.y); p[6] = f2bf(b.z); p[7] = f2bf(b.w);
  *(u16x8*)&wbf[i] = p;
}

// ---------------------------------------------------------------------------
// Kernel 2: MoE GEMM v10.
// R9 post-mortem (VGPR 148, NO spill, 132us, MfmaUtil 20%, Occ 11%):
//  (a) SQ_LDS_BANK_CONFLICT 4718592 = EXACTLY 4 per ds_read_b128
//      (1,179,648 reads/dispatch). Cross-round: 16-row frags + plain r&7
//      swizzle (R1) = 0; 32-row + extended r&7^((r>>3)&3) (R3/R4) = 0;
//      mismatched combos (R2, R7-R9) = 4/read. v10 reverts to the PLAIN
//      r&7 swizzle matching our 16-row fragment reads (R1-proven).
//  (b) Occupancy was GRID-bound: 512 blocks = 2 blocks/CU (LDS allowed 3).
//      v10: BN 128->64 -> grid 128x8 = 1024 blocks; LDS 16+2x8+4 = 36 KB
//      -> 4 blocks/CU, zero tail (1024 = 4*256). Each XCD owns one 64-dout
//      column: B slice 512 KB L2-resident. acc halves to 32 regs
//      (live ~115; <=128 would give 16 waves/CU).
// Kept: h-outer/e-inner (A staged once per K-chunk), 16x16x32 mfma with
// 4 independent 2-deep chains per oi, oi-outer (wf 8 regs live), bias in
// epilogue, one barrier per t, e-loop unroll 2 (R9: no spill), unpinned.
// ---------------------------------------------------------------------------
__global__ __launch_bounds__(256) void moe_gemm_kernel(
    const u16* __restrict__ xbf, const u16* __restrict__ wbf,
    const float* __restrict__ coeffsT, const float* __restrict__ ebias,
    float* __restrict__ out) {
  __shared__ __align__(16) u16 As[BM * BK];        // 16 KB (X, single buf)
  __shared__ __align__(16) u16 Bs[2][BN * BK];     // 16 KB (W, dbuf)
  __shared__ __align__(16) float cS[KE * BM];      // 4 KB  coeffs slice

  const int tid = threadIdx.x;
  const int wave = tid >> 6, lane = tid & 63;

  // XCD mapping: b&7 = xcd owns dout column xcd*64 (512 KB B slice, L2);
  // s = b>>3 in [0,128) walks m-tiles contiguously within the XCD.
  const int b = blockIdx.x;
  const int xcd = b & 7, sq = b >> 3;
  const int m0 = sq * BM;                       // token base
  const int n0 = xcd * BN;                      // dout base

  const int wt = (wave >> 1) * 64;   // wave's token offset: {0,64}
  const int wo = (wave & 1) * 32;    // wave's dout  offset: {0,32}

  const int lr = lane & 15, lq = lane >> 4;     // frag row / k-quad
  const int l31 = lane & 31, l5 = lane >> 5;    // prologue cS staging
  const int lrow = lane >> 3, l7 = lane & 7;    // staging row/chunk

  // PLAIN swizzle (R1-proven for 16-row frag reads): LDS slot s of row r
  // holds global chunk s ^ (r&7). Store: source col = (l7^lrow)*8, same
  // for every GLOAD j (j*8 doesn't change r&7). Read key = lr&7.
  const int s0 = (l7 ^ lrow) * 8;
  const int key = lr & 7;
  const u16* aRow = xbf + (size_t)(m0 + wave * 32 + lrow) * DIN;
  const u16* bRow = wbf + (size_t)(n0 + wave * 16 + lrow) * DIN;

  // ---- prologue staging: X_0 (4 GLOADs), W_(h0,e0) (2), coeffs slice ----
#pragma unroll
  for (int j = 0; j < 4; ++j)
    GLOAD_LDS16(aRow + (size_t)(j * 8) * DIN + s0,
                &As[(wave * 32 + j * 8) * BK]);
#pragma unroll
  for (int j = 0; j < 2; ++j)
    GLOAD_LDS16(bRow + (size_t)(j * 8) * DIN + s0,
                &Bs[0][(wave * 16 + j * 8) * BK]);
  // cS[e][i] = coeffsT[e][m0+i]; wave w covers e in {2w,2w+1}
  GLOAD_LDS16(coeffsT + (size_t)(wave * 2 + l5) * NTOK + m0 + l31 * 4,
              &cS[wave * 256]);
  __syncthreads();

  const f32x4 vz = {};
  f32x4 acc[2][4] = {};   // [oi][ti], 32 regs
  bf16x8 xf[4][2];        // X frags for chunk h: [ti][kh], 32 regs

#pragma unroll 1
  for (int h = 0; h < 8; ++h) {
#pragma unroll 2
    for (int e = 0; e < KE; ++e) {
      // ---- STAGE next W tile into Bs[(e+1)&1] ----
      if (e < 7 || h < 7) {
        const size_t off = (e < 7)
            ? (size_t)(e + 1) * ESTRIDE + (size_t)h * 64
            : (size_t)(h + 1) * 64;   // wraps to expert 0, chunk h+1
#pragma unroll
        for (int j = 0; j < 2; ++j)
          GLOAD_LDS16(bRow + (size_t)(j * 8) * DIN + s0 + off,
                      &Bs[(e + 1) & 1][(wave * 16 + j * 8) * BK]);
      }
      // ---- STAGE X_{h+1} at e==1 (reads of As at e==0 barrier-separated)
      if (e == 1 && h < 7) {
#pragma unroll
        for (int j = 0; j < 4; ++j)
          GLOAD_LDS16(aRow + (size_t)(j * 8) * DIN + s0 +
                          (size_t)(h + 1) * 64,
                      &As[(wave * 32 + j * 8) * BK]);
      }

      // ---- X fragments (chunk h) once per h ----
      if (e == 0) {
#pragma unroll
        for (int ti = 0; ti < 4; ++ti)
#pragma unroll
          for (int kh = 0; kh < 2; ++kh)
            xf[ti][kh] = *(const bf16x8*)
                &As[(wt + ti * 16 + lr) * BK + ((kh * 4 + lq) ^ key) * 8];
      }

      // per-token coefficient scalars (broadcast ds_reads)
      float cv[4];
#pragma unroll
      for (int ti = 0; ti < 4; ++ti) cv[ti] = cS[e * BM + wt + ti * 16 + lr];

      // ---- COMPUTE + FOLD, oi-outer (only wf[2] live: 8 regs).
      // Per oi: unrolled ti loop = 4 independent 2-deep MFMA chains. ----
      const u16* Bp = Bs[e & 1];
#pragma unroll
      for (int oi = 0; oi < 2; ++oi) {
        bf16x8 wf0 = *(const bf16x8*)
            &Bp[(wo + oi * 16 + lr) * BK + ((0 * 4 + lq) ^ key) * 8];
        bf16x8 wf1 = *(const bf16x8*)
            &Bp[(wo + oi * 16 + lr) * BK + ((1 * 4 + lq) ^ key) * 8];
#pragma unroll
        for (int ti = 0; ti < 4; ++ti) {
          f32x4 pp;
          pp = __builtin_amdgcn_mfma_f32_16x16x32_bf16(
              wf0, xf[ti][0], vz, 0, 0, 0);
          pp = __builtin_amdgcn_mfma_f32_16x16x32_bf16(
              wf1, xf[ti][1], pp, 0, 0, 0);
#pragma unroll
          for (int r = 0; r < 4; ++r)
            acc[oi][ti][r] += cv[ti] * pp[r];
        }
      }
      __syncthreads();   // Bs[e&1] reads done before t+1 overwrites it
    }
  }

  // ---- epilogue: bias fold  acc[o,tok] += Sum_e c[e][tok]*beta[e][o] ----
  // (ebias read from global: 16 KB, L2-hot, once)
#pragma unroll
  for (int e = 0; e < KE; ++e) {
    float cv[4];
#pragma unroll
    for (int ti = 0; ti < 4; ++ti) cv[ti] = cS[e * BM + wt + ti * 16 + lr];
#pragma unroll
    for (int oi = 0; oi < 2; ++oi) {
      const f32x4 bb =
          *(const f32x4*)&ebias[e * DOUT + n0 + wo + oi * 16 + lq * 4];
#pragma unroll
      for (int ti = 0; ti < 4; ++ti)
#pragma unroll
        for (int r = 0; r < 4; ++r)
          acc[oi][ti][r] += cv[ti] * bb[r];
    }
  }

  // ---- stores: D[o, tok] -> out[tok, o]; 16x16 C/D: col=lr(tok),
  // row=lq*4+r (o, contiguous) -> one f32x4 store per frag ----
#pragma unroll
  for (int ti = 0; ti < 4; ++ti) {
    const size_t rowbase = (size_t)(m0 + wt + ti * 16 + lr) * DOUT;
#pragma unroll
    for (int oi = 0; oi < 2; ++oi)
      *(f32x4*)&out[rowbase + n0 + wo + oi * 16 + lq * 4] = acc[oi][ti];
  }
}

// ---------------------------------------------------------------------------
extern "C" void kernel_launch(void* const* d_in, const int* in_sizes, int n_in,
                              void* d_out, int out_size, void* d_ws,
                              size_t ws_size, hipStream_t stream) {
  (void)in_sizes; (void)n_in; (void)out_size; (void)ws_size;
  const float* x  = (const float*)d_in[0];   // [4,4096,512]
  const float* ew = (const float*)d_in[1];   // [8,512,512]
  const float* eb = (const float*)d_in[2];   // [8,512]
  const float* mw = (const float*)d_in[3];   // [8,512]
  const float* mb = (const float*)d_in[4];   // [8]
  float* out = (float*)d_out;                // [4,4096,512]

  // workspace layout: xbf 16 MB | wbf 4 MB | coeffsT 0.5 MB  (~20.5 MB)
  u16* xbf = (u16*)d_ws;
  u16* wbf = (u16*)((char*)d_ws + (size_t)NTOK * DIN * 2);
  float* coeffsT =
      (float*)((char*)d_ws + (size_t)NTOK * DIN * 2 + (size_t)KE * DOUT * DIN * 2);

  hipLaunchKernelGGL(gate_kernel, dim3(GATE_BLOCKS), dim3(256), 0, stream,
                     x, mw, mb, xbf, coeffsT);
  hipLaunchKernelGGL(wcast_kernel, dim3(WCONV_BLOCKS), dim3(256), 0, stream,
                     ew, wbf);
  hipLaunchKernelGGL(moe_gemm_kernel, dim3((NTOK / BM) * (DOUT / BN)),
                     dim3(256), 0, stream, xbf, wbf, coeffsT, eb, out);
}